// Round 1
// baseline (3133.829 us; speedup 1.0000x reference)
//
#include <hip/hip_runtime.h>

namespace {
constexpr int G_  = 2048;
constexpr int HID = 128;
constexpr int NVv = 500000, NIv = 300000, NTv = 50000, NAv = 50000, NSv = 10000;
constexpr int EVTv = 500000, EIVv = 1500000, EVIv = 1500000, EVAv = 500000, ETSv = 50000, EIIv = 600000;
}

// ---------------------------------------------------------------------------
// Edge scatter: thread = (edge, feature). Wave of 64 lanes covers one 256B row
// (D=64) -> coalesced gather; scatter via fp32 global atomics. Lane d==0 also
// bumps the dst count.
// ---------------------------------------------------------------------------
template<int D>
__global__ __launch_bounds__(256)
void edge_scatter(const int* __restrict__ src, const int* __restrict__ dst,
                  const float* __restrict__ xs,
                  float* __restrict__ sum, float* __restrict__ cnt, int E)
{
    constexpr int LOG = (D == 64) ? 6 : 5;
    int i = blockIdx.x * 256 + threadIdx.x;
    if (i >= E * D) return;           // E*D <= 96M, fits int
    int e = i >> LOG;
    int d = i & (D - 1);
    int s = src[e];
    int t = dst[e];
    float v = xs[s * D + d];
    atomicAdd(&sum[t * D + d], v);
    if (d == 0) atomicAdd(&cnt[t], 1.0f);
}

__global__ __launch_bounds__(256)
void batch_count(const int* __restrict__ batch, float* __restrict__ cnt, int N)
{
    int i = blockIdx.x * 256 + threadIdx.x;
    if (i < N) atomicAdd(&cnt[batch[i]], 1.0f);
}

__device__ __forceinline__ float4 ld4(const float* p) { return *(const float4*)p; }
__device__ __forceinline__ float4 add4(float4 a, float4 b) {
    return make_float4(a.x + b.x, a.y + b.y, a.z + b.z, a.w + b.w);
}

// acc[i][c] += sum_{kk=0..3} sh[(ng*4+i)*STRIDE + k + kk] * w_kk[c]
template<int STRIDE>
__device__ __forceinline__ void tile_fma(float (&acc)[4][4], const float* __restrict__ sh,
                                         float4 w0, float4 w1, float4 w2, float4 w3,
                                         int k, int ng)
{
#pragma unroll
    for (int i = 0; i < 4; ++i) {
        const float4 a = *(const float4*)&sh[(ng * 4 + i) * STRIDE + k];
        acc[i][0] += a.x * w0.x + a.y * w1.x + a.z * w2.x + a.w * w3.x;
        acc[i][1] += a.x * w0.y + a.y * w1.y + a.z * w2.y + a.w * w3.y;
        acc[i][2] += a.x * w0.z + a.y * w1.z + a.z * w2.z + a.w * w3.z;
        acc[i][3] += a.x * w0.w + a.y * w1.w + a.z * w2.w + a.w * w3.w;
    }
}

// ---------------------------------------------------------------------------
// Fused per-node-type kernel:
//   h = relu(agg/cnt @ Wl + bl + x @ Wr [+ agg2/cnt2 @ Wl2 + bl2 + x @ Wr2])
//   z = h @ nW + nb ;  atomic pool_sum[batch[n]] += z (run-length reduced)
// Block = 128 threads, 16 nodes/block. Thread = 4 nodes x 4 columns.
// All N are divisible by 16 -> no tail guards.
// ---------------------------------------------------------------------------
template<int DS, int DD, bool HAS2>
__global__ __launch_bounds__(128)
void sage_node(const float* __restrict__ agg,  const float* __restrict__ cnt,
               const float* __restrict__ xd,
               const float* __restrict__ Wl,   const float* __restrict__ bl,
               const float* __restrict__ Wr,
               const float* __restrict__ agg2, const float* __restrict__ cnt2,
               const float* __restrict__ Wl2,  const float* __restrict__ bl2,
               const float* __restrict__ Wr2,
               const float* __restrict__ nW,   const float* __restrict__ nb,
               const int* __restrict__ batch,
               float* __restrict__ pool_sum, int N)
{
    constexpr int NPB = 16;
    __shared__ __align__(16) float a_sh[NPB * DS];
    __shared__ __align__(16) float x_sh[NPB * DD];
    __shared__ __align__(16) float a2_sh[HAS2 ? NPB * DS : 4];
    __shared__ __align__(16) float h_sh[NPB * HID];
    __shared__ float inv_sh[NPB];
    __shared__ float inv2_sh[HAS2 ? NPB : 4];
    __shared__ int   batch_sh[NPB];

    const int tid = threadIdx.x;
    const int jg  = tid & 31;   // column group: cols 4*jg .. 4*jg+3
    const int ng  = tid >> 5;   // node subgroup: nodes ng*4 .. ng*4+3
    const int node0 = blockIdx.x * NPB;

    if (tid < NPB) {
        int n = node0 + tid;
        inv_sh[tid]   = 1.0f / fmaxf(cnt[n], 1.0f);
        batch_sh[tid] = batch[n];
        if constexpr (HAS2) inv2_sh[tid] = 1.0f / fmaxf(cnt2[n], 1.0f);
    }
    __syncthreads();

    for (int i = tid; i < NPB * DS; i += 128)
        a_sh[i] = agg[node0 * DS + i] * inv_sh[i / DS];
    if constexpr (HAS2) {
        for (int i = tid; i < NPB * DS; i += 128)
            a2_sh[i] = agg2[node0 * DS + i] * inv2_sh[i / DS];
    }
    for (int i = tid; i < NPB * DD; i += 128)
        x_sh[i] = xd[node0 * DD + i];
    __syncthreads();

    float acc[4][4];
#pragma unroll
    for (int i = 0; i < 4; ++i)
#pragma unroll
        for (int c = 0; c < 4; ++c) acc[i][c] = 0.f;

    // mean-agg @ Wl
#pragma unroll 2
    for (int k = 0; k < DS; k += 4) {
        float4 w0 = ld4(&Wl[(k + 0) * HID + jg * 4]);
        float4 w1 = ld4(&Wl[(k + 1) * HID + jg * 4]);
        float4 w2 = ld4(&Wl[(k + 2) * HID + jg * 4]);
        float4 w3 = ld4(&Wl[(k + 3) * HID + jg * 4]);
        tile_fma<DS>(acc, a_sh, w0, w1, w2, w3, k, ng);
    }
    // x_dst @ Wr (+ Wr2 folded in for the instruction type)
#pragma unroll 2
    for (int k = 0; k < DD; k += 4) {
        float4 w0 = ld4(&Wr[(k + 0) * HID + jg * 4]);
        float4 w1 = ld4(&Wr[(k + 1) * HID + jg * 4]);
        float4 w2 = ld4(&Wr[(k + 2) * HID + jg * 4]);
        float4 w3 = ld4(&Wr[(k + 3) * HID + jg * 4]);
        if constexpr (HAS2) {
            w0 = add4(w0, ld4(&Wr2[(k + 0) * HID + jg * 4]));
            w1 = add4(w1, ld4(&Wr2[(k + 1) * HID + jg * 4]));
            w2 = add4(w2, ld4(&Wr2[(k + 2) * HID + jg * 4]));
            w3 = add4(w3, ld4(&Wr2[(k + 3) * HID + jg * 4]));
        }
        tile_fma<DD>(acc, x_sh, w0, w1, w2, w3, k, ng);
    }
    if constexpr (HAS2) {
#pragma unroll 2
        for (int k = 0; k < DS; k += 4) {
            float4 w0 = ld4(&Wl2[(k + 0) * HID + jg * 4]);
            float4 w1 = ld4(&Wl2[(k + 1) * HID + jg * 4]);
            float4 w2 = ld4(&Wl2[(k + 2) * HID + jg * 4]);
            float4 w3 = ld4(&Wl2[(k + 3) * HID + jg * 4]);
            tile_fma<DS>(acc, a2_sh, w0, w1, w2, w3, k, ng);
        }
    }

    float4 blv = ld4(&bl[jg * 4]);
    if constexpr (HAS2) blv = add4(blv, ld4(&bl2[jg * 4]));

#pragma unroll
    for (int i = 0; i < 4; ++i) {
        float4 h;
        h.x = fmaxf(acc[i][0] + blv.x, 0.f);
        h.y = fmaxf(acc[i][1] + blv.y, 0.f);
        h.z = fmaxf(acc[i][2] + blv.z, 0.f);
        h.w = fmaxf(acc[i][3] + blv.w, 0.f);
        *(float4*)&h_sh[(ng * 4 + i) * HID + jg * 4] = h;
    }
    __syncthreads();

    // z = h @ nW (+ nb later)
#pragma unroll
    for (int i = 0; i < 4; ++i)
#pragma unroll
        for (int c = 0; c < 4; ++c) acc[i][c] = 0.f;

#pragma unroll 2
    for (int k = 0; k < HID; k += 4) {
        float4 w0 = ld4(&nW[(k + 0) * HID + jg * 4]);
        float4 w1 = ld4(&nW[(k + 1) * HID + jg * 4]);
        float4 w2 = ld4(&nW[(k + 2) * HID + jg * 4]);
        float4 w3 = ld4(&nW[(k + 3) * HID + jg * 4]);
        tile_fma<HID>(acc, h_sh, w0, w1, w2, w3, k, ng);
    }

    float4 nbv = ld4(&nb[jg * 4]);
    // run-length reduce over this thread's 4 consecutive nodes, then atomics
    float4 run = make_float4(acc[0][0] + nbv.x, acc[0][1] + nbv.y,
                             acc[0][2] + nbv.z, acc[0][3] + nbv.w);
    int curg = batch_sh[ng * 4];
#pragma unroll
    for (int i = 1; i < 4; ++i) {
        int g = batch_sh[ng * 4 + i];
        float4 z = make_float4(acc[i][0] + nbv.x, acc[i][1] + nbv.y,
                               acc[i][2] + nbv.z, acc[i][3] + nbv.w);
        if (g != curg) {
            float* p = &pool_sum[curg * HID + jg * 4];
            atomicAdd(p + 0, run.x); atomicAdd(p + 1, run.y);
            atomicAdd(p + 2, run.z); atomicAdd(p + 3, run.w);
            run = z; curg = g;
        } else {
            run = add4(run, z);
        }
    }
    {
        float* p = &pool_sum[curg * HID + jg * 4];
        atomicAdd(p + 0, run.x); atomicAdd(p + 1, run.y);
        atomicAdd(p + 2, run.z); atomicAdd(p + 3, run.w);
    }
}

// ---------------------------------------------------------------------------
// out[g][o] = gb[o] + sum_{t,j} (pool_sum[t][g][j]/max(cnt,1)) * gW[(t*128+j)*64+o]
// ---------------------------------------------------------------------------
__global__ __launch_bounds__(64)
void final_kernel(const float* __restrict__ pool_sum, const float* __restrict__ pool_cnt,
                  const float* __restrict__ gW, const float* __restrict__ gb,
                  float* __restrict__ out)
{
    __shared__ float p_sh[5 * HID];
    int g = blockIdx.x, tid = threadIdx.x;
    for (int i = tid; i < 5 * HID; i += 64) {
        int t  = i >> 7;
        int jj = i & 127;
        float c = fmaxf(pool_cnt[t * G_ + g], 1.0f);
        p_sh[i] = pool_sum[((size_t)t * G_ + g) * HID + jj] / c;
    }
    __syncthreads();
    float acc = gb[tid];
#pragma unroll 8
    for (int k = 0; k < 5 * HID; ++k)
        acc += p_sh[k] * gW[k * 64 + tid];
    out[g * 64 + tid] = acc;
}

// ---------------------------------------------------------------------------
extern "C" void kernel_launch(void* const* d_in, const int* in_sizes, int n_in,
                              void* d_out, int out_size, void* d_ws, size_t ws_size,
                              hipStream_t stream)
{
    const float* x_value       = (const float*)d_in[0];
    const float* x_typ         = (const float*)d_in[1];
    const float* x_size_       = (const float*)d_in[2];
    const float* x_attribute   = (const float*)d_in[3];
    const float* x_instruction = (const float*)d_in[4];
    const float* Wl_vt = (const float*)d_in[5];
    const float* bl_vt = (const float*)d_in[6];
    const float* Wr_vt = (const float*)d_in[7];
    const float* Wl_iv = (const float*)d_in[8];
    const float* bl_iv = (const float*)d_in[9];
    const float* Wr_iv = (const float*)d_in[10];
    const float* Wl_vi = (const float*)d_in[11];
    const float* bl_vi = (const float*)d_in[12];
    const float* Wr_vi = (const float*)d_in[13];
    const float* Wl_va = (const float*)d_in[14];
    const float* bl_va = (const float*)d_in[15];
    const float* Wr_va = (const float*)d_in[16];
    const float* Wl_ts = (const float*)d_in[17];
    const float* bl_ts = (const float*)d_in[18];
    const float* Wr_ts = (const float*)d_in[19];
    const float* Wl_ii = (const float*)d_in[20];
    const float* bl_ii = (const float*)d_in[21];
    const float* Wr_ii = (const float*)d_in[22];
    const float* nW_typ         = (const float*)d_in[23];
    const float* nb_typ         = (const float*)d_in[24];
    const float* nW_value       = (const float*)d_in[25];
    const float* nb_value       = (const float*)d_in[26];
    const float* nW_instruction = (const float*)d_in[27];
    const float* nb_instruction = (const float*)d_in[28];
    const float* nW_attribute   = (const float*)d_in[29];
    const float* nb_attribute   = (const float*)d_in[30];
    const float* nW_size        = (const float*)d_in[31];
    const float* nb_size        = (const float*)d_in[32];
    const float* gW = (const float*)d_in[33];
    const float* gb = (const float*)d_in[34];
    const int* src_vt = (const int*)d_in[35];
    const int* dst_vt = (const int*)d_in[36];
    const int* src_iv = (const int*)d_in[37];
    const int* dst_iv = (const int*)d_in[38];
    const int* src_vi = (const int*)d_in[39];
    const int* dst_vi = (const int*)d_in[40];
    const int* src_va = (const int*)d_in[41];
    const int* dst_va = (const int*)d_in[42];
    const int* src_ts = (const int*)d_in[43];
    const int* dst_ts = (const int*)d_in[44];
    const int* src_ii = (const int*)d_in[45];
    const int* dst_ii = (const int*)d_in[46];
    const int* batch_typ         = (const int*)d_in[47];
    const int* batch_value       = (const int*)d_in[48];
    const int* batch_instruction = (const int*)d_in[49];
    const int* batch_attribute   = (const int*)d_in[50];
    const int* batch_size        = (const int*)d_in[51];

    float* ws = (float*)d_ws;
    size_t off = 0;
    float* agg_vt = ws + off; off += (size_t)NTv * 64;
    float* agg_iv = ws + off; off += (size_t)NVv * 64;
    float* agg_vi = ws + off; off += (size_t)NIv * 64;
    float* agg_va = ws + off; off += (size_t)NAv * 64;
    float* agg_ts = ws + off; off += (size_t)NSv * 32;
    float* agg_ii = ws + off; off += (size_t)NIv * 64;
    float* cnt_vt = ws + off; off += NTv;
    float* cnt_iv = ws + off; off += NVv;
    float* cnt_vi = ws + off; off += NIv;
    float* cnt_va = ws + off; off += NAv;
    float* cnt_ts = ws + off; off += NSv;
    float* cnt_ii = ws + off; off += NIv;
    float* pool_sum = ws + off; off += (size_t)5 * G_ * HID;
    float* pool_cnt = ws + off; off += (size_t)5 * G_;
    size_t total_bytes = off * sizeof(float);   // ~318.6 MB

    hipMemsetAsync(d_ws, 0, total_bytes, stream);

    edge_scatter<64><<<(EVTv * 64) / 256, 256, 0, stream>>>(src_vt, dst_vt, x_value,       agg_vt, cnt_vt, EVTv);
    edge_scatter<64><<<(EIVv * 64) / 256, 256, 0, stream>>>(src_iv, dst_iv, x_instruction, agg_iv, cnt_iv, EIVv);
    edge_scatter<64><<<(EVIv * 64) / 256, 256, 0, stream>>>(src_vi, dst_vi, x_value,       agg_vi, cnt_vi, EVIv);
    edge_scatter<64><<<(EVAv * 64) / 256, 256, 0, stream>>>(src_va, dst_va, x_value,       agg_va, cnt_va, EVAv);
    edge_scatter<32><<<(ETSv * 32) / 256, 256, 0, stream>>>(src_ts, dst_ts, x_typ,         agg_ts, cnt_ts, ETSv);
    edge_scatter<64><<<(EIIv * 64) / 256, 256, 0, stream>>>(src_ii, dst_ii, x_instruction, agg_ii, cnt_ii, EIIv);

    batch_count<<<(NTv + 255) / 256, 256, 0, stream>>>(batch_typ,         pool_cnt + 0 * G_, NTv);
    batch_count<<<(NVv + 255) / 256, 256, 0, stream>>>(batch_value,       pool_cnt + 1 * G_, NVv);
    batch_count<<<(NIv + 255) / 256, 256, 0, stream>>>(batch_instruction, pool_cnt + 2 * G_, NIv);
    batch_count<<<(NAv + 255) / 256, 256, 0, stream>>>(batch_attribute,   pool_cnt + 3 * G_, NAv);
    batch_count<<<(NSv + 255) / 256, 256, 0, stream>>>(batch_size,        pool_cnt + 4 * G_, NSv);

    sage_node<64, 32, false><<<NTv / 16, 128, 0, stream>>>(
        agg_vt, cnt_vt, x_typ, Wl_vt, bl_vt, Wr_vt,
        nullptr, nullptr, nullptr, nullptr, nullptr,
        nW_typ, nb_typ, batch_typ, pool_sum + (size_t)0 * G_ * HID, NTv);
    sage_node<64, 64, false><<<NVv / 16, 128, 0, stream>>>(
        agg_iv, cnt_iv, x_value, Wl_iv, bl_iv, Wr_iv,
        nullptr, nullptr, nullptr, nullptr, nullptr,
        nW_value, nb_value, batch_value, pool_sum + (size_t)1 * G_ * HID, NVv);
    sage_node<64, 64, true><<<NIv / 16, 128, 0, stream>>>(
        agg_vi, cnt_vi, x_instruction, Wl_vi, bl_vi, Wr_vi,
        agg_ii, cnt_ii, Wl_ii, bl_ii, Wr_ii,
        nW_instruction, nb_instruction, batch_instruction, pool_sum + (size_t)2 * G_ * HID, NIv);
    sage_node<64, 32, false><<<NAv / 16, 128, 0, stream>>>(
        agg_va, cnt_va, x_attribute, Wl_va, bl_va, Wr_va,
        nullptr, nullptr, nullptr, nullptr, nullptr,
        nW_attribute, nb_attribute, batch_attribute, pool_sum + (size_t)3 * G_ * HID, NAv);
    sage_node<32, 32, false><<<NSv / 16, 128, 0, stream>>>(
        agg_ts, cnt_ts, x_size_, Wl_ts, bl_ts, Wr_ts,
        nullptr, nullptr, nullptr, nullptr, nullptr,
        nW_size, nb_size, batch_size, pool_sum + (size_t)4 * G_ * HID, NSv);

    final_kernel<<<G_, 64, 0, stream>>>(pool_sum, pool_cnt, gW, gb, (float*)d_out);
}

// Round 2
// 2453.700 us; speedup vs baseline: 1.2772x; 1.2772x over previous
//
#include <hip/hip_runtime.h>

namespace {
constexpr int G_  = 2048;
constexpr int HID = 128;
constexpr int NVv = 500000, NIv = 300000, NTv = 50000, NAv = 50000, NSv = 10000;
constexpr int EVTv = 500000, EIVv = 1500000, EVIv = 1500000, EVAv = 500000, ETSv = 50000, EIIv = 600000;
}

typedef short s16x8 __attribute__((ext_vector_type(8)));
typedef float f32x4 __attribute__((ext_vector_type(4)));

__device__ __forceinline__ float4 ld4(const float* p) { return *(const float4*)p; }

__device__ __forceinline__ unsigned short f2bf(float x) {
    unsigned u = __float_as_uint(x);
    u += 0x7fffu + ((u >> 16) & 1u);
    return (unsigned short)(u >> 16);
}

// ---------------------------------------------------------------------------
// Edge scatter (unchanged): thread = (edge, feature); fp32 atomic scatter.
// ---------------------------------------------------------------------------
template<int D>
__global__ __launch_bounds__(256)
void edge_scatter(const int* __restrict__ src, const int* __restrict__ dst,
                  const float* __restrict__ xs,
                  float* __restrict__ sum, float* __restrict__ cnt, int E)
{
    constexpr int LOG = (D == 64) ? 6 : 5;
    int i = blockIdx.x * 256 + threadIdx.x;
    if (i >= E * D) return;
    int e = i >> LOG;
    int d = i & (D - 1);
    int s = src[e];
    int t = dst[e];
    float v = xs[s * D + d];
    atomicAdd(&sum[t * D + d], v);
    if (d == 0) atomicAdd(&cnt[t], 1.0f);
}

__global__ __launch_bounds__(256)
void batch_count(const int* __restrict__ batch, float* __restrict__ cnt, int N)
{
    int i = blockIdx.x * 256 + threadIdx.x;
    if (i < N) atomicAdd(&cnt[batch[i]], 1.0f);
}

// ---------------------------------------------------------------------------
// Weight prep: out[n*K1+k] = bf16 of W1[k][n], W1 rows = [S0(L0) | S1(L1) | S2(+S2b)]
// ---------------------------------------------------------------------------
__global__ __launch_bounds__(256)
void prep_wt(const float* __restrict__ S0, int L0,
             const float* __restrict__ S1, int L1,
             const float* __restrict__ S2, const float* __restrict__ S2b,
             unsigned short* __restrict__ out, int K1)
{
    int i = blockIdx.x * 256 + threadIdx.x;
    if (i >= 128 * K1) return;
    int n = i / K1, k = i - n * K1;
    float v;
    if (k < L0) v = S0[k * 128 + n];
    else if (k < L0 + L1) v = S1[(k - L0) * 128 + n];
    else {
        int kk = k - L0 - L1;
        v = S2[kk * 128 + n];
        if (S2b) v += S2b[kk * 128 + n];
    }
    out[i] = f2bf(v);
}

// ---------------------------------------------------------------------------
// Fused MFMA node kernel. Block = 256 thr (4 waves), 64 nodes.
// A-tile rows = [agg/cnt | (agg2/cnt2) | x] as bf16 in swizzled LDS.
// h = relu(A @ W1 + b1) -> bf16 LDS (wave-private rows) -> z = h @ nW + nb
// -> run-length reduced atomic pooling into pool_sum[batch][128].
// ---------------------------------------------------------------------------
template<int DSa, int DD, bool HAS2, int ASTR, int K1>
__global__ __launch_bounds__(256)
void sage_mfma(const float* __restrict__ agg,  const float* __restrict__ cnt,
               const float* __restrict__ agg2, const float* __restrict__ cnt2,
               const float* __restrict__ xd,
               const unsigned short* __restrict__ W1T,
               const float* __restrict__ bl, const float* __restrict__ bl2,
               const unsigned short* __restrict__ nWT,
               const float* __restrict__ nbp,
               const int* __restrict__ batch,
               float* __restrict__ pool_sum, int N)
{
    constexpr int KST  = K1 / 32;
    constexpr int XOFF = HAS2 ? 2 * DSa : DSa;
    __shared__ __align__(16) unsigned short a_sh[64 * ASTR];
    __shared__ __align__(16) unsigned short h_sh[64 * 128];

    const int tid   = threadIdx.x;
    const int node0 = blockIdx.x * 64;

    // ---- build A tile (bf16, swizzled) ----
    constexpr int C4 = K1 / 4;          // float4 chunks per row
    constexpr int CH = 64 * C4 / 256;   // chunks per thread (integer for all types)
#pragma unroll
    for (int j = 0; j < CH; ++j) {
        int c   = j * 256 + tid;
        int r   = c / C4;
        int col = (c - r * C4) * 4;
        int node = node0 + r;
        float4 v = make_float4(0.f, 0.f, 0.f, 0.f);
        if (node < N) {
            if (col < DSa) {
                float inv = 1.0f / fmaxf(cnt[node], 1.0f);
                v = ld4(&agg[node * DSa + col]);
                v.x *= inv; v.y *= inv; v.z *= inv; v.w *= inv;
            } else {
                bool second = HAS2 && (col < 2 * DSa);
                if (second) {
                    float inv = 1.0f / fmaxf(cnt2[node], 1.0f);
                    v = ld4(&agg2[node * DSa + col - DSa]);
                    v.x *= inv; v.y *= inv; v.z *= inv; v.w *= inv;
                } else {
                    v = ld4(&xd[node * DD + col - XOFF]);
                }
            }
        }
        unsigned p0 = (unsigned)f2bf(v.x) | ((unsigned)f2bf(v.y) << 16);
        unsigned p1 = (unsigned)f2bf(v.z) | ((unsigned)f2bf(v.w) << 16);
        unsigned byte = ((unsigned)(r * ASTR + col) * 2u) ^ ((unsigned)(r & 7) << 4);
        *(uint2*)((char*)a_sh + byte) = make_uint2(p0, p1);
    }
    __syncthreads();

    const int w  = tid >> 6;
    const int l  = tid & 63;
    const int lg = l >> 4;
    const int lr = l & 15;
    const int rowA = w * 16 + lr;
    const unsigned swz = (unsigned)(rowA & 7) << 4;

    // ---- stage 1: h = A @ W1 ----
    f32x4 acc[8];
#pragma unroll
    for (int nb = 0; nb < 8; ++nb) acc[nb] = (f32x4){0.f, 0.f, 0.f, 0.f};

#pragma unroll
    for (int ks = 0; ks < KST; ++ks) {
        s16x8 af = *(const s16x8*)((const char*)a_sh +
                     (((unsigned)(rowA * ASTR + ks * 32 + lg * 8) * 2u) ^ swz));
#pragma unroll
        for (int nb = 0; nb < 8; ++nb) {
            s16x8 bf = *(const s16x8*)&W1T[(nb * 16 + lr) * K1 + ks * 32 + lg * 8];
            acc[nb] = __builtin_amdgcn_mfma_f32_16x16x32_bf16(af, bf, acc[nb], 0, 0, 0);
        }
    }

    // ---- bias + relu -> bf16 h in LDS (wave-private rows) ----
#pragma unroll
    for (int nb = 0; nb < 8; ++nb) {
        int col = nb * 16 + lr;
        float b = bl[col];
        if constexpr (HAS2) b += bl2[col];
#pragma unroll
        for (int rg = 0; rg < 4; ++rg) {
            float hv = fmaxf(acc[nb][rg] + b, 0.0f);
            int row = w * 16 + lg * 4 + rg;
            unsigned byte = ((unsigned)(row * 128 + col) * 2u) ^ ((unsigned)(row & 7) << 4);
            *(unsigned short*)((char*)h_sh + byte) = f2bf(hv);
        }
    }
    __syncthreads();

    // ---- stage 2: z = h @ nW ----
    f32x4 acc2[8];
#pragma unroll
    for (int nb = 0; nb < 8; ++nb) acc2[nb] = (f32x4){0.f, 0.f, 0.f, 0.f};

#pragma unroll
    for (int ks = 0; ks < 4; ++ks) {
        s16x8 hf = *(const s16x8*)((const char*)h_sh +
                     (((unsigned)(rowA * 128 + ks * 32 + lg * 8) * 2u) ^ swz));
#pragma unroll
        for (int nb = 0; nb < 8; ++nb) {
            s16x8 bf = *(const s16x8*)&nWT[(nb * 16 + lr) * 128 + ks * 32 + lg * 8];
            acc2[nb] = __builtin_amdgcn_mfma_f32_16x16x32_bf16(hf, bf, acc2[nb], 0, 0, 0);
        }
    }

    // ---- pool: z rows are (lane>>4)*4+reg; run-length reduce then atomics ----
    const int base = node0 + w * 16 + lg * 4;
    float nbias[8];
#pragma unroll
    for (int nb = 0; nb < 8; ++nb) nbias[nb] = nbp[nb * 16 + lr];

    int bt[4];
#pragma unroll
    for (int rg = 0; rg < 4; ++rg) bt[rg] = (base + rg < N) ? batch[base + rg] : -1;

    float run[8];
    int cur = bt[0];
#pragma unroll
    for (int nb = 0; nb < 8; ++nb) run[nb] = acc2[nb][0] + nbias[nb];
#pragma unroll
    for (int rg = 1; rg < 4; ++rg) {
        if (bt[rg] == cur) {
#pragma unroll
            for (int nb = 0; nb < 8; ++nb) run[nb] += acc2[nb][rg] + nbias[nb];
        } else {
            if (cur >= 0) {
#pragma unroll
                for (int nb = 0; nb < 8; ++nb)
                    atomicAdd(&pool_sum[cur * 128 + nb * 16 + lr], run[nb]);
            }
            cur = bt[rg];
#pragma unroll
            for (int nb = 0; nb < 8; ++nb) run[nb] = acc2[nb][rg] + nbias[nb];
        }
    }
    if (cur >= 0) {
#pragma unroll
        for (int nb = 0; nb < 8; ++nb)
            atomicAdd(&pool_sum[cur * 128 + nb * 16 + lr], run[nb]);
    }
}

// ---------------------------------------------------------------------------
__global__ __launch_bounds__(64)
void final_kernel(const float* __restrict__ pool_sum, const float* __restrict__ pool_cnt,
                  const float* __restrict__ gW, const float* __restrict__ gb,
                  float* __restrict__ out)
{
    __shared__ float p_sh[5 * HID];
    int g = blockIdx.x, tid = threadIdx.x;
    for (int i = tid; i < 5 * HID; i += 64) {
        int t  = i >> 7;
        int jj = i & 127;
        float c = fmaxf(pool_cnt[t * G_ + g], 1.0f);
        p_sh[i] = pool_sum[((size_t)t * G_ + g) * HID + jj] / c;
    }
    __syncthreads();
    float acc = gb[tid];
#pragma unroll 8
    for (int k = 0; k < 5 * HID; ++k)
        acc += p_sh[k] * gW[k * 64 + tid];
    out[g * 64 + tid] = acc;
}

// ---------------------------------------------------------------------------
extern "C" void kernel_launch(void* const* d_in, const int* in_sizes, int n_in,
                              void* d_out, int out_size, void* d_ws, size_t ws_size,
                              hipStream_t stream)
{
    const float* x_value       = (const float*)d_in[0];
    const float* x_typ         = (const float*)d_in[1];
    const float* x_size_       = (const float*)d_in[2];
    const float* x_attribute   = (const float*)d_in[3];
    const float* x_instruction = (const float*)d_in[4];
    const float* Wl_vt = (const float*)d_in[5];
    const float* bl_vt = (const float*)d_in[6];
    const float* Wr_vt = (const float*)d_in[7];
    const float* Wl_iv = (const float*)d_in[8];
    const float* bl_iv = (const float*)d_in[9];
    const float* Wr_iv = (const float*)d_in[10];
    const float* Wl_vi = (const float*)d_in[11];
    const float* bl_vi = (const float*)d_in[12];
    const float* Wr_vi = (const float*)d_in[13];
    const float* Wl_va = (const float*)d_in[14];
    const float* bl_va = (const float*)d_in[15];
    const float* Wr_va = (const float*)d_in[16];
    const float* Wl_ts = (const float*)d_in[17];
    const float* bl_ts = (const float*)d_in[18];
    const float* Wr_ts = (const float*)d_in[19];
    const float* Wl_ii = (const float*)d_in[20];
    const float* bl_ii = (const float*)d_in[21];
    const float* Wr_ii = (const float*)d_in[22];
    const float* nW_typ         = (const float*)d_in[23];
    const float* nb_typ         = (const float*)d_in[24];
    const float* nW_value       = (const float*)d_in[25];
    const float* nb_value       = (const float*)d_in[26];
    const float* nW_instruction = (const float*)d_in[27];
    const float* nb_instruction = (const float*)d_in[28];
    const float* nW_attribute   = (const float*)d_in[29];
    const float* nb_attribute   = (const float*)d_in[30];
    const float* nW_size        = (const float*)d_in[31];
    const float* nb_size        = (const float*)d_in[32];
    const float* gW = (const float*)d_in[33];
    const float* gb = (const float*)d_in[34];
    const int* src_vt = (const int*)d_in[35];
    const int* dst_vt = (const int*)d_in[36];
    const int* src_iv = (const int*)d_in[37];
    const int* dst_iv = (const int*)d_in[38];
    const int* src_vi = (const int*)d_in[39];
    const int* dst_vi = (const int*)d_in[40];
    const int* src_va = (const int*)d_in[41];
    const int* dst_va = (const int*)d_in[42];
    const int* src_ts = (const int*)d_in[43];
    const int* dst_ts = (const int*)d_in[44];
    const int* src_ii = (const int*)d_in[45];
    const int* dst_ii = (const int*)d_in[46];
    const int* batch_typ         = (const int*)d_in[47];
    const int* batch_value       = (const int*)d_in[48];
    const int* batch_instruction = (const int*)d_in[49];
    const int* batch_attribute   = (const int*)d_in[50];
    const int* batch_size        = (const int*)d_in[51];

    float* ws = (float*)d_ws;
    size_t off = 0;
    float* agg_vt = ws + off; off += (size_t)NTv * 64;
    float* agg_iv = ws + off; off += (size_t)NVv * 64;
    float* agg_vi = ws + off; off += (size_t)NIv * 64;
    float* agg_va = ws + off; off += (size_t)NAv * 64;
    float* agg_ts = ws + off; off += (size_t)NSv * 32;
    float* agg_ii = ws + off; off += (size_t)NIv * 64;
    float* cnt_vt = ws + off; off += NTv;
    float* cnt_iv = ws + off; off += NVv;
    float* cnt_vi = ws + off; off += NIv;
    float* cnt_va = ws + off; off += NAv;
    float* cnt_ts = ws + off; off += NSv;
    float* cnt_ii = ws + off; off += NIv;
    float* pool_sum = ws + off; off += (size_t)5 * G_ * HID;
    float* pool_cnt = ws + off; off += (size_t)5 * G_;
    size_t zero_bytes = off * sizeof(float);   // ~318.6 MB (atomic accumulators)

    // bf16 transposed weights appended after the zeroed region
    unsigned short* wt = (unsigned short*)(ws + off);
    size_t wo = 0;
    unsigned short* w1t_vt = wt + wo; wo += 128 * 96;
    unsigned short* w1t_iv = wt + wo; wo += 128 * 128;
    unsigned short* w1t_vi = wt + wo; wo += 128 * 192;
    unsigned short* w1t_va = wt + wo; wo += 128 * 96;
    unsigned short* w1t_ts = wt + wo; wo += 128 * 64;
    unsigned short* nwt_t  = wt + wo; wo += 128 * 128;
    unsigned short* nwt_v  = wt + wo; wo += 128 * 128;
    unsigned short* nwt_i  = wt + wo; wo += 128 * 128;
    unsigned short* nwt_a  = wt + wo; wo += 128 * 128;
    unsigned short* nwt_s  = wt + wo; wo += 128 * 128;

    hipMemsetAsync(d_ws, 0, zero_bytes, stream);

    // weight prep (tiny)
    prep_wt<<<(128 *  96 + 255) / 256, 256, 0, stream>>>(Wl_vt, 64, nullptr, 0, Wr_vt, nullptr, w1t_vt,  96);
    prep_wt<<<(128 * 128 + 255) / 256, 256, 0, stream>>>(Wl_iv, 64, nullptr, 0, Wr_iv, nullptr, w1t_iv, 128);
    prep_wt<<<(128 * 192 + 255) / 256, 256, 0, stream>>>(Wl_vi, 64, Wl_ii, 64, Wr_vi, Wr_ii,   w1t_vi, 192);
    prep_wt<<<(128 *  96 + 255) / 256, 256, 0, stream>>>(Wl_va, 64, nullptr, 0, Wr_va, nullptr, w1t_va,  96);
    prep_wt<<<(128 *  64 + 255) / 256, 256, 0, stream>>>(Wl_ts, 32, nullptr, 0, Wr_ts, nullptr, w1t_ts,  64);
    prep_wt<<<(128 * 128 + 255) / 256, 256, 0, stream>>>(nW_typ,         128, nullptr, 0, nullptr, nullptr, nwt_t, 128);
    prep_wt<<<(128 * 128 + 255) / 256, 256, 0, stream>>>(nW_value,       128, nullptr, 0, nullptr, nullptr, nwt_v, 128);
    prep_wt<<<(128 * 128 + 255) / 256, 256, 0, stream>>>(nW_instruction, 128, nullptr, 0, nullptr, nullptr, nwt_i, 128);
    prep_wt<<<(128 * 128 + 255) / 256, 256, 0, stream>>>(nW_attribute,   128, nullptr, 0, nullptr, nullptr, nwt_a, 128);
    prep_wt<<<(128 * 128 + 255) / 256, 256, 0, stream>>>(nW_size,        128, nullptr, 0, nullptr, nullptr, nwt_s, 128);

    edge_scatter<64><<<(EVTv * 64) / 256, 256, 0, stream>>>(src_vt, dst_vt, x_value,       agg_vt, cnt_vt, EVTv);
    edge_scatter<64><<<(EIVv * 64) / 256, 256, 0, stream>>>(src_iv, dst_iv, x_instruction, agg_iv, cnt_iv, EIVv);
    edge_scatter<64><<<(EVIv * 64) / 256, 256, 0, stream>>>(src_vi, dst_vi, x_value,       agg_vi, cnt_vi, EVIv);
    edge_scatter<64><<<(EVAv * 64) / 256, 256, 0, stream>>>(src_va, dst_va, x_value,       agg_va, cnt_va, EVAv);
    edge_scatter<32><<<(ETSv * 32) / 256, 256, 0, stream>>>(src_ts, dst_ts, x_typ,         agg_ts, cnt_ts, ETSv);
    edge_scatter<64><<<(EIIv * 64) / 256, 256, 0, stream>>>(src_ii, dst_ii, x_instruction, agg_ii, cnt_ii, EIIv);

    batch_count<<<(NTv + 255) / 256, 256, 0, stream>>>(batch_typ,         pool_cnt + 0 * G_, NTv);
    batch_count<<<(NVv + 255) / 256, 256, 0, stream>>>(batch_value,       pool_cnt + 1 * G_, NVv);
    batch_count<<<(NIv + 255) / 256, 256, 0, stream>>>(batch_instruction, pool_cnt + 2 * G_, NIv);
    batch_count<<<(NAv + 255) / 256, 256, 0, stream>>>(batch_attribute,   pool_cnt + 3 * G_, NAv);
    batch_count<<<(NSv + 255) / 256, 256, 0, stream>>>(batch_size,        pool_cnt + 4 * G_, NSv);

    sage_mfma<64, 32, false, 128,  96><<<(NTv + 63) / 64, 256, 0, stream>>>(
        agg_vt, cnt_vt, nullptr, nullptr, x_typ, w1t_vt, bl_vt, nullptr,
        nwt_t, nb_typ, batch_typ, pool_sum + (size_t)0 * G_ * HID, NTv);
    sage_mfma<64, 64, false, 128, 128><<<(NVv + 63) / 64, 256, 0, stream>>>(
        agg_iv, cnt_iv, nullptr, nullptr, x_value, w1t_iv, bl_iv, nullptr,
        nwt_v, nb_value, batch_value, pool_sum + (size_t)1 * G_ * HID, NVv);
    sage_mfma<64, 64, true,  192, 192><<<(NIv + 63) / 64, 256, 0, stream>>>(
        agg_vi, cnt_vi, agg_ii, cnt_ii, x_instruction, w1t_vi, bl_vi, bl_ii,
        nwt_i, nb_instruction, batch_instruction, pool_sum + (size_t)2 * G_ * HID, NIv);
    sage_mfma<64, 32, false, 128,  96><<<(NAv + 63) / 64, 256, 0, stream>>>(
        agg_va, cnt_va, nullptr, nullptr, x_attribute, w1t_va, bl_va, nullptr,
        nwt_a, nb_attribute, batch_attribute, pool_sum + (size_t)3 * G_ * HID, NAv);
    sage_mfma<32, 32, false,  64,  64><<<(NSv + 63) / 64, 256, 0, stream>>>(
        agg_ts, cnt_ts, nullptr, nullptr, x_size_, w1t_ts, bl_ts, nullptr,
        nwt_s, nb_size, batch_size, pool_sum + (size_t)4 * G_ * HID, NSv);

    final_kernel<<<G_, 64, 0, stream>>>(pool_sum, pool_cnt, gW, gb, (float*)d_out);
}

// Round 3
// 2127.968 us; speedup vs baseline: 1.4727x; 1.1531x over previous
//
#include <hip/hip_runtime.h>

namespace {
constexpr int G_  = 2048;
constexpr int HID = 128;
constexpr int NVv = 500000, NIv = 300000, NTv = 50000, NAv = 50000, NSv = 10000;
constexpr int EVTv = 500000, EIVv = 1500000, EVIv = 1500000, EVAv = 500000, ETSv = 50000, EIIv = 600000;
// concatenated per-(edge-type,dst-node) CSR space
constexpr int OFF_VT = 0;
constexpr int OFF_IV = OFF_VT + NTv;          // 50000
constexpr int OFF_VI = OFF_IV + NVv;          // 550000
constexpr int OFF_VA = OFF_VI + NIv;          // 850000
constexpr int OFF_TS = OFF_VA + NAv;          // 900000
constexpr int OFF_II = OFF_TS + NSv;          // 910000
constexpr int TOT_N  = OFF_II + NIv;          // 1210000
constexpr int TOT_E  = EVTv + EIVv + EVIv + EVAv + ETSv + EIIv;  // 4650000
constexpr int NCH    = (TOT_N + 1023) / 1024; // 1182
}

typedef short s16x8 __attribute__((ext_vector_type(8)));
typedef float f32x4 __attribute__((ext_vector_type(4)));

__device__ __forceinline__ float4 ld4(const float* p) { return *(const float4*)p; }

__device__ __forceinline__ unsigned short f2bf(float x) {
    unsigned u = __float_as_uint(x);
    u += 0x7fffu + ((u >> 16) & 1u);
    return (unsigned short)(u >> 16);
}

// ---------------------------------------------------------------------------
// CSR build
// ---------------------------------------------------------------------------
__global__ __launch_bounds__(256)
void edge_hist(const int* __restrict__ dst, int* __restrict__ deg, int off, int E)
{
    int i = blockIdx.x * 256 + threadIdx.x;
    if (i < E) atomicAdd(&deg[off + dst[i]], 1);
}

__global__ __launch_bounds__(256)
void scan_chunk_sum(const int* __restrict__ deg, int* __restrict__ csum)
{
    __shared__ int sc[256];
    int blk = blockIdx.x, tid = threadIdx.x;
    int base = blk * 1024 + tid * 4;
    int s = 0;
#pragma unroll
    for (int k = 0; k < 4; ++k) { int idx = base + k; if (idx < TOT_N) s += deg[idx]; }
    sc[tid] = s; __syncthreads();
    for (int d = 128; d > 0; d >>= 1) {
        if (tid < d) sc[tid] += sc[tid + d];
        __syncthreads();
    }
    if (tid == 0) csum[blk] = sc[0];
}

__global__ __launch_bounds__(256)
void scan_offsets(const int* __restrict__ csum, int* __restrict__ coff)
{
    __shared__ int sc[256];
    int tid = threadIdx.x;
    int s[5]; int tsum = 0;
#pragma unroll
    for (int k = 0; k < 5; ++k) { int idx = tid * 5 + k; s[k] = (idx < NCH) ? csum[idx] : 0; tsum += s[k]; }
    sc[tid] = tsum; __syncthreads();
    for (int d = 1; d < 256; d <<= 1) {
        int v = (tid >= d) ? sc[tid - d] : 0;
        __syncthreads();
        sc[tid] += v;
        __syncthreads();
    }
    int run = sc[tid] - tsum;   // exclusive
#pragma unroll
    for (int k = 0; k < 5; ++k) { int idx = tid * 5 + k; if (idx < NCH) coff[idx] = run; run += s[k]; }
}

__global__ __launch_bounds__(256)
void scan_write(const int* __restrict__ deg, const int* __restrict__ coff, int* __restrict__ cur)
{
    __shared__ int sc[256];
    int blk = blockIdx.x, tid = threadIdx.x;
    int base = blk * 1024 + tid * 4;
    int v[4]; int tsum = 0;
#pragma unroll
    for (int k = 0; k < 4; ++k) { int idx = base + k; v[k] = (idx < TOT_N) ? deg[idx] : 0; tsum += v[k]; }
    sc[tid] = tsum; __syncthreads();
    for (int d = 1; d < 256; d <<= 1) {
        int t = (tid >= d) ? sc[tid - d] : 0;
        __syncthreads();
        sc[tid] += t;
        __syncthreads();
    }
    int run = coff[blk] + sc[tid] - tsum;   // global exclusive prefix
#pragma unroll
    for (int k = 0; k < 4; ++k) { int idx = base + k; if (idx < TOT_N) cur[idx] = run; run += v[k]; }
}

__global__ __launch_bounds__(256)
void edge_pos(const int* __restrict__ src, const int* __restrict__ dst,
              int* __restrict__ cur, int* __restrict__ eidx, int off, int E)
{
    int i = blockIdx.x * 256 + threadIdx.x;
    if (i < E) {
        int p = atomicAdd(&cur[off + dst[i]], 1);
        eidx[p] = src[i];
    }
}

__global__ __launch_bounds__(256)
void batch_count(const int* __restrict__ batch, float* __restrict__ cnt, int N)
{
    int i = blockIdx.x * 256 + threadIdx.x;
    if (i < N) atomicAdd(&cnt[batch[i]], 1.0f);
}

// ---------------------------------------------------------------------------
// Weight prep: out[n*K1+k] = bf16 of W1[k][n], W1 rows = [S0(L0) | S1(L1) | S2(+S2b)]
// ---------------------------------------------------------------------------
__global__ __launch_bounds__(256)
void prep_wt(const float* __restrict__ S0, int L0,
             const float* __restrict__ S1, int L1,
             const float* __restrict__ S2, const float* __restrict__ S2b,
             unsigned short* __restrict__ out, int K1)
{
    int i = blockIdx.x * 256 + threadIdx.x;
    if (i >= 128 * K1) return;
    int n = i / K1, k = i - n * K1;
    float v;
    if (k < L0) v = S0[k * 128 + n];
    else if (k < L0 + L1) v = S1[(k - L0) * 128 + n];
    else {
        int kk = k - L0 - L1;
        v = S2[kk * 128 + n];
        if (S2b) v += S2b[kk * 128 + n];
    }
    out[i] = f2bf(v);
}

// ---------------------------------------------------------------------------
// Fused CSR-gather + MFMA node kernel. Block = 256 thr (4 waves), 64 nodes.
// A-tile rows = [mean_csr1 | (mean_csr2) | x_dst] as bf16 in swizzled LDS;
// the means are gathered in-place from the feature tables via CSR.
// h = relu(A @ W1 + b1) -> bf16 LDS -> z = h @ nW + nb -> pooled atomics.
// ---------------------------------------------------------------------------
template<int DSa, int DD, bool HAS2, int ASTR, int K1>
__global__ __launch_bounds__(256)
void sage_mfma(const int* __restrict__ deg, const int* __restrict__ cur,
               const int* __restrict__ eidx, int off1, int off2,
               const float* __restrict__ xs1, const float* __restrict__ xs2,
               const float* __restrict__ xd,
               const unsigned short* __restrict__ W1T,
               const float* __restrict__ bl, const float* __restrict__ bl2,
               const unsigned short* __restrict__ nWT,
               const float* __restrict__ nbp,
               const int* __restrict__ batch,
               float* __restrict__ pool_sum, int N)
{
    constexpr int KST  = K1 / 32;
    constexpr int XOFF = HAS2 ? 2 * DSa : DSa;
    __shared__ __align__(16) unsigned short a_sh[64 * ASTR];
    __shared__ __align__(16) unsigned short h_sh[64 * 128];

    const int tid   = threadIdx.x;
    const int node0 = blockIdx.x * 64;

    // ---- build A tile: CSR mean gather + dst features, bf16 swizzled ----
    constexpr int C4 = K1 / 4;
    constexpr int CH = 64 * C4 / 256;
#pragma unroll
    for (int j = 0; j < CH; ++j) {
        int c   = j * 256 + tid;
        int r   = c / C4;
        int col = (c - r * C4) * 4;
        int node = node0 + r;
        float4 v = make_float4(0.f, 0.f, 0.f, 0.f);
        if (node < N) {
            if (col < DSa) {
                int e = cur[off1 + node];
                int d = deg[off1 + node];
                const int* lst = eidx + (e - d);
                float4 a = make_float4(0.f, 0.f, 0.f, 0.f);
                for (int t = 0; t < d; ++t) {
                    int s = lst[t];
                    float4 xv = ld4(&xs1[s * DSa + col]);
                    a.x += xv.x; a.y += xv.y; a.z += xv.z; a.w += xv.w;
                }
                float inv = 1.0f / fmaxf((float)d, 1.0f);
                v = make_float4(a.x * inv, a.y * inv, a.z * inv, a.w * inv);
            } else if (HAS2 && col < 2 * DSa) {
                int e = cur[off2 + node];
                int d = deg[off2 + node];
                const int* lst = eidx + (e - d);
                float4 a = make_float4(0.f, 0.f, 0.f, 0.f);
                for (int t = 0; t < d; ++t) {
                    int s = lst[t];
                    float4 xv = ld4(&xs2[s * DSa + col - DSa]);
                    a.x += xv.x; a.y += xv.y; a.z += xv.z; a.w += xv.w;
                }
                float inv = 1.0f / fmaxf((float)d, 1.0f);
                v = make_float4(a.x * inv, a.y * inv, a.z * inv, a.w * inv);
            } else {
                v = ld4(&xd[node * DD + col - XOFF]);
            }
        }
        unsigned p0 = (unsigned)f2bf(v.x) | ((unsigned)f2bf(v.y) << 16);
        unsigned p1 = (unsigned)f2bf(v.z) | ((unsigned)f2bf(v.w) << 16);
        unsigned byte = ((unsigned)(r * ASTR + col) * 2u) ^ ((unsigned)(r & 7) << 4);
        *(uint2*)((char*)a_sh + byte) = make_uint2(p0, p1);
    }
    __syncthreads();

    const int w  = tid >> 6;
    const int l  = tid & 63;
    const int lg = l >> 4;
    const int lr = l & 15;
    const int rowA = w * 16 + lr;
    const unsigned swz = (unsigned)(rowA & 7) << 4;

    // ---- stage 1: h = A @ W1 ----
    f32x4 acc[8];
#pragma unroll
    for (int nb = 0; nb < 8; ++nb) acc[nb] = (f32x4){0.f, 0.f, 0.f, 0.f};

#pragma unroll
    for (int ks = 0; ks < KST; ++ks) {
        s16x8 af = *(const s16x8*)((const char*)a_sh +
                     (((unsigned)(rowA * ASTR + ks * 32 + lg * 8) * 2u) ^ swz));
#pragma unroll
        for (int nb = 0; nb < 8; ++nb) {
            s16x8 bf = *(const s16x8*)&W1T[(nb * 16 + lr) * K1 + ks * 32 + lg * 8];
            acc[nb] = __builtin_amdgcn_mfma_f32_16x16x32_bf16(af, bf, acc[nb], 0, 0, 0);
        }
    }

    // ---- bias + relu -> bf16 h in LDS ----
#pragma unroll
    for (int nb = 0; nb < 8; ++nb) {
        int col = nb * 16 + lr;
        float b = bl[col];
        if constexpr (HAS2) b += bl2[col];
#pragma unroll
        for (int rg = 0; rg < 4; ++rg) {
            float hv = fmaxf(acc[nb][rg] + b, 0.0f);
            int row = w * 16 + lg * 4 + rg;
            unsigned byte = ((unsigned)(row * 128 + col) * 2u) ^ ((unsigned)(row & 7) << 4);
            *(unsigned short*)((char*)h_sh + byte) = f2bf(hv);
        }
    }
    __syncthreads();

    // ---- stage 2: z = h @ nW ----
    f32x4 acc2[8];
#pragma unroll
    for (int nb = 0; nb < 8; ++nb) acc2[nb] = (f32x4){0.f, 0.f, 0.f, 0.f};

#pragma unroll
    for (int ks = 0; ks < 4; ++ks) {
        s16x8 hf = *(const s16x8*)((const char*)h_sh +
                     (((unsigned)(rowA * 128 + ks * 32 + lg * 8) * 2u) ^ swz));
#pragma unroll
        for (int nb = 0; nb < 8; ++nb) {
            s16x8 bf = *(const s16x8*)&nWT[(nb * 16 + lr) * 128 + ks * 32 + lg * 8];
            acc2[nb] = __builtin_amdgcn_mfma_f32_16x16x32_bf16(hf, bf, acc2[nb], 0, 0, 0);
        }
    }

    // ---- pool: run-length reduce over 4 consecutive rows, then atomics ----
    const int base = node0 + w * 16 + lg * 4;
    float nbias[8];
#pragma unroll
    for (int nb = 0; nb < 8; ++nb) nbias[nb] = nbp[nb * 16 + lr];

    int bt[4];
#pragma unroll
    for (int rg = 0; rg < 4; ++rg) bt[rg] = (base + rg < N) ? batch[base + rg] : -1;

    float run[8];
    int cb = bt[0];
#pragma unroll
    for (int nb = 0; nb < 8; ++nb) run[nb] = acc2[nb][0] + nbias[nb];
#pragma unroll
    for (int rg = 1; rg < 4; ++rg) {
        if (bt[rg] == cb) {
#pragma unroll
            for (int nb = 0; nb < 8; ++nb) run[nb] += acc2[nb][rg] + nbias[nb];
        } else {
            if (cb >= 0) {
#pragma unroll
                for (int nb = 0; nb < 8; ++nb)
                    atomicAdd(&pool_sum[cb * 128 + nb * 16 + lr], run[nb]);
            }
            cb = bt[rg];
#pragma unroll
            for (int nb = 0; nb < 8; ++nb) run[nb] = acc2[nb][rg] + nbias[nb];
        }
    }
    if (cb >= 0) {
#pragma unroll
        for (int nb = 0; nb < 8; ++nb)
            atomicAdd(&pool_sum[cb * 128 + nb * 16 + lr], run[nb]);
    }
}

// ---------------------------------------------------------------------------
__global__ __launch_bounds__(64)
void final_kernel(const float* __restrict__ pool_sum, const float* __restrict__ pool_cnt,
                  const float* __restrict__ gW, const float* __restrict__ gb,
                  float* __restrict__ out)
{
    __shared__ float p_sh[5 * HID];
    int g = blockIdx.x, tid = threadIdx.x;
    for (int i = tid; i < 5 * HID; i += 64) {
        int t  = i >> 7;
        int jj = i & 127;
        float c = fmaxf(pool_cnt[t * G_ + g], 1.0f);
        p_sh[i] = pool_sum[((size_t)t * G_ + g) * HID + jj] / c;
    }
    __syncthreads();
    float acc = gb[tid];
#pragma unroll 8
    for (int k = 0; k < 5 * HID; ++k)
        acc += p_sh[k] * gW[k * 64 + tid];
    out[g * 64 + tid] = acc;
}

// ---------------------------------------------------------------------------
extern "C" void kernel_launch(void* const* d_in, const int* in_sizes, int n_in,
                              void* d_out, int out_size, void* d_ws, size_t ws_size,
                              hipStream_t stream)
{
    const float* x_value       = (const float*)d_in[0];
    const float* x_typ         = (const float*)d_in[1];
    const float* x_size_       = (const float*)d_in[2];
    const float* x_attribute   = (const float*)d_in[3];
    const float* x_instruction = (const float*)d_in[4];
    const float* Wl_vt = (const float*)d_in[5];
    const float* bl_vt = (const float*)d_in[6];
    const float* Wr_vt = (const float*)d_in[7];
    const float* Wl_iv = (const float*)d_in[8];
    const float* bl_iv = (const float*)d_in[9];
    const float* Wr_iv = (const float*)d_in[10];
    const float* Wl_vi = (const float*)d_in[11];
    const float* bl_vi = (const float*)d_in[12];
    const float* Wr_vi = (const float*)d_in[13];
    const float* Wl_va = (const float*)d_in[14];
    const float* bl_va = (const float*)d_in[15];
    const float* Wr_va = (const float*)d_in[16];
    const float* Wl_ts = (const float*)d_in[17];
    const float* bl_ts = (const float*)d_in[18];
    const float* Wr_ts = (const float*)d_in[19];
    const float* Wl_ii = (const float*)d_in[20];
    const float* bl_ii = (const float*)d_in[21];
    const float* Wr_ii = (const float*)d_in[22];
    const float* nW_typ         = (const float*)d_in[23];
    const float* nb_typ         = (const float*)d_in[24];
    const float* nW_value       = (const float*)d_in[25];
    const float* nb_value       = (const float*)d_in[26];
    const float* nW_instruction = (const float*)d_in[27];
    const float* nb_instruction = (const float*)d_in[28];
    const float* nW_attribute   = (const float*)d_in[29];
    const float* nb_attribute   = (const float*)d_in[30];
    const float* nW_size        = (const float*)d_in[31];
    const float* nb_size        = (const float*)d_in[32];
    const float* gW = (const float*)d_in[33];
    const float* gb = (const float*)d_in[34];
    const int* src_vt = (const int*)d_in[35];
    const int* dst_vt = (const int*)d_in[36];
    const int* src_iv = (const int*)d_in[37];
    const int* dst_iv = (const int*)d_in[38];
    const int* src_vi = (const int*)d_in[39];
    const int* dst_vi = (const int*)d_in[40];
    const int* src_va = (const int*)d_in[41];
    const int* dst_va = (const int*)d_in[42];
    const int* src_ts = (const int*)d_in[43];
    const int* dst_ts = (const int*)d_in[44];
    const int* src_ii = (const int*)d_in[45];
    const int* dst_ii = (const int*)d_in[46];
    const int* batch_typ         = (const int*)d_in[47];
    const int* batch_value       = (const int*)d_in[48];
    const int* batch_instruction = (const int*)d_in[49];
    const int* batch_attribute   = (const int*)d_in[50];
    const int* batch_size        = (const int*)d_in[51];

    // ---- workspace layout ----
    int* deg = (int*)d_ws;                                   // TOT_N (zeroed)
    float* pool_sum = (float*)(deg + TOT_N);                 // 5*G*HID (zeroed)
    float* pool_cnt = pool_sum + (size_t)5 * G_ * HID;       // 5*G (zeroed)
    size_t zero_bytes = (size_t)TOT_N * 4 + ((size_t)5 * G_ * HID + 5 * G_) * 4;

    int* cur  = (int*)(pool_cnt + 5 * G_);                   // TOT_N
    int* csum = cur + TOT_N;                                 // NCH
    int* coff = csum + NCH;                                  // NCH
    int* eidx = coff + NCH;                                  // TOT_E
    // 64B-align the bf16 weight region
    unsigned short* wt = (unsigned short*)(((uintptr_t)(eidx + TOT_E) + 63) & ~(uintptr_t)63);
    size_t wo = 0;
    unsigned short* w1t_vt = wt + wo; wo += 128 * 96;
    unsigned short* w1t_iv = wt + wo; wo += 128 * 128;
    unsigned short* w1t_vi = wt + wo; wo += 128 * 192;
    unsigned short* w1t_va = wt + wo; wo += 128 * 96;
    unsigned short* w1t_ts = wt + wo; wo += 128 * 64;
    unsigned short* nwt_t  = wt + wo; wo += 128 * 128;
    unsigned short* nwt_v  = wt + wo; wo += 128 * 128;
    unsigned short* nwt_i  = wt + wo; wo += 128 * 128;
    unsigned short* nwt_a  = wt + wo; wo += 128 * 128;
    unsigned short* nwt_s  = wt + wo; wo += 128 * 128;

    hipMemsetAsync(d_ws, 0, zero_bytes, stream);

    // weight prep (tiny)
    prep_wt<<<(128 *  96 + 255) / 256, 256, 0, stream>>>(Wl_vt, 64, nullptr, 0, Wr_vt, nullptr, w1t_vt,  96);
    prep_wt<<<(128 * 128 + 255) / 256, 256, 0, stream>>>(Wl_iv, 64, nullptr, 0, Wr_iv, nullptr, w1t_iv, 128);
    prep_wt<<<(128 * 192 + 255) / 256, 256, 0, stream>>>(Wl_vi, 64, Wl_ii, 64, Wr_vi, Wr_ii,   w1t_vi, 192);
    prep_wt<<<(128 *  96 + 255) / 256, 256, 0, stream>>>(Wl_va, 64, nullptr, 0, Wr_va, nullptr, w1t_va,  96);
    prep_wt<<<(128 *  64 + 255) / 256, 256, 0, stream>>>(Wl_ts, 32, nullptr, 0, Wr_ts, nullptr, w1t_ts,  64);
    prep_wt<<<(128 * 128 + 255) / 256, 256, 0, stream>>>(nW_typ,         128, nullptr, 0, nullptr, nullptr, nwt_t, 128);
    prep_wt<<<(128 * 128 + 255) / 256, 256, 0, stream>>>(nW_value,       128, nullptr, 0, nullptr, nullptr, nwt_v, 128);
    prep_wt<<<(128 * 128 + 255) / 256, 256, 0, stream>>>(nW_instruction, 128, nullptr, 0, nullptr, nullptr, nwt_i, 128);
    prep_wt<<<(128 * 128 + 255) / 256, 256, 0, stream>>>(nW_attribute,   128, nullptr, 0, nullptr, nullptr, nwt_a, 128);
    prep_wt<<<(128 * 128 + 255) / 256, 256, 0, stream>>>(nW_size,        128, nullptr, 0, nullptr, nullptr, nwt_s, 128);

    // CSR build: histogram -> scan -> position scatter
    edge_hist<<<(EVTv + 255) / 256, 256, 0, stream>>>(dst_vt, deg, OFF_VT, EVTv);
    edge_hist<<<(EIVv + 255) / 256, 256, 0, stream>>>(dst_iv, deg, OFF_IV, EIVv);
    edge_hist<<<(EVIv + 255) / 256, 256, 0, stream>>>(dst_vi, deg, OFF_VI, EVIv);
    edge_hist<<<(EVAv + 255) / 256, 256, 0, stream>>>(dst_va, deg, OFF_VA, EVAv);
    edge_hist<<<(ETSv + 255) / 256, 256, 0, stream>>>(dst_ts, deg, OFF_TS, ETSv);
    edge_hist<<<(EIIv + 255) / 256, 256, 0, stream>>>(dst_ii, deg, OFF_II, EIIv);

    scan_chunk_sum<<<NCH, 256, 0, stream>>>(deg, csum);
    scan_offsets<<<1, 256, 0, stream>>>(csum, coff);
    scan_write<<<NCH, 256, 0, stream>>>(deg, coff, cur);

    edge_pos<<<(EVTv + 255) / 256, 256, 0, stream>>>(src_vt, dst_vt, cur, eidx, OFF_VT, EVTv);
    edge_pos<<<(EIVv + 255) / 256, 256, 0, stream>>>(src_iv, dst_iv, cur, eidx, OFF_IV, EIVv);
    edge_pos<<<(EVIv + 255) / 256, 256, 0, stream>>>(src_vi, dst_vi, cur, eidx, OFF_VI, EVIv);
    edge_pos<<<(EVAv + 255) / 256, 256, 0, stream>>>(src_va, dst_va, cur, eidx, OFF_VA, EVAv);
    edge_pos<<<(ETSv + 255) / 256, 256, 0, stream>>>(src_ts, dst_ts, cur, eidx, OFF_TS, ETSv);
    edge_pos<<<(EIIv + 255) / 256, 256, 0, stream>>>(src_ii, dst_ii, cur, eidx, OFF_II, EIIv);

    batch_count<<<(NTv + 255) / 256, 256, 0, stream>>>(batch_typ,         pool_cnt + 0 * G_, NTv);
    batch_count<<<(NVv + 255) / 256, 256, 0, stream>>>(batch_value,       pool_cnt + 1 * G_, NVv);
    batch_count<<<(NIv + 255) / 256, 256, 0, stream>>>(batch_instruction, pool_cnt + 2 * G_, NIv);
    batch_count<<<(NAv + 255) / 256, 256, 0, stream>>>(batch_attribute,   pool_cnt + 3 * G_, NAv);
    batch_count<<<(NSv + 255) / 256, 256, 0, stream>>>(batch_size,        pool_cnt + 4 * G_, NSv);

    // fused gather + node GEMMs
    sage_mfma<64, 32, false, 128,  96><<<(NTv + 63) / 64, 256, 0, stream>>>(
        deg, cur, eidx, OFF_VT, 0, x_value, nullptr, x_typ,
        w1t_vt, bl_vt, nullptr, nwt_t, nb_typ, batch_typ,
        pool_sum + (size_t)0 * G_ * HID, NTv);
    sage_mfma<64, 64, false, 128, 128><<<(NVv + 63) / 64, 256, 0, stream>>>(
        deg, cur, eidx, OFF_IV, 0, x_instruction, nullptr, x_value,
        w1t_iv, bl_iv, nullptr, nwt_v, nb_value, batch_value,
        pool_sum + (size_t)1 * G_ * HID, NVv);
    sage_mfma<64, 64, true,  192, 192><<<(NIv + 63) / 64, 256, 0, stream>>>(
        deg, cur, eidx, OFF_VI, OFF_II, x_value, x_instruction, x_instruction,
        w1t_vi, bl_vi, bl_ii, nwt_i, nb_instruction, batch_instruction,
        pool_sum + (size_t)2 * G_ * HID, NIv);
    sage_mfma<64, 32, false, 128,  96><<<(NAv + 63) / 64, 256, 0, stream>>>(
        deg, cur, eidx, OFF_VA, 0, x_value, nullptr, x_attribute,
        w1t_va, bl_va, nullptr, nwt_a, nb_attribute, batch_attribute,
        pool_sum + (size_t)3 * G_ * HID, NAv);
    sage_mfma<32, 32, false,  64,  64><<<(NSv + 63) / 64, 256, 0, stream>>>(
        deg, cur, eidx, OFF_TS, 0, x_typ, nullptr, x_size_,
        w1t_ts, bl_ts, nullptr, nwt_s, nb_size, batch_size,
        pool_sum + (size_t)4 * G_ * HID, NSv);

    final_kernel<<<G_, 64, 0, stream>>>(pool_sum, pool_cnt, gW, gb, (float*)d_out);
}